// Round 1
// baseline (759.459 us; speedup 1.0000x reference)
//
#include <hip/hip_runtime.h>
#include <hip/hip_bf16.h>

#define BB 16
#define CC 384
#define HH 56
#define WW 56
#define PLANE (HH*WW)
#define NHW (BB*PLANE)
#define SW 92      // LDS row stride (floats) for kernel1: 92/4=23 granules, odd -> bank-quad spread
#define ROWS 86    // 15 + 56 + 15
#define COL0 16    // center col offset (16 so 16B alignment holds; halo needs only 15)
#define ROW0 15
#define ST3 61     // kernel3 LDS stride (odd)

// ---------------- Kernel 1: 31x31 depthwise conv + stats (+5x5 stats) ----------------
__global__ __launch_bounds__(256) void conv_large_k(
    const float* __restrict__ x, const float* __restrict__ wL,
    const float* __restrict__ wS,
    __hip_bfloat16* __restrict__ yL, float* __restrict__ stats)
{
    __shared__ float in_s[ROWS * SW];   // 86*92*4 = 31648 B
    __shared__ float w_s[31 * 32];      // padded weight rows, 3968 B
    __shared__ float w2_s[25];
    __shared__ float red_s[16];         // 4 waves x 4 stats

    const int bid = blockIdx.x;
    const int c   = bid % CC;
    const int tid = threadIdx.x;

    // zero LDS input buffer (7912 floats, multiple of 4)
    for (int i = tid * 4; i < ROWS * SW; i += 256 * 4) {
        *(float4*)&in_s[i] = make_float4(0.f, 0.f, 0.f, 0.f);
    }
    // load 31x31 weights into padded 31x32 layout
    for (int i = tid; i < 992; i += 256) {
        int kx = i & 31;
        int ky = i >> 5;
        w_s[i] = (kx < 31) ? wL[c * 961 + ky * 31 + kx] : 0.f;
    }
    if (tid < 25) w2_s[tid] = wS[c * 25 + tid];
    __syncthreads();

    // load plane center: 784 float4 (56%4==0 so no row crossing)
    const float4* xp = (const float4*)(x + (size_t)bid * PLANE);
    for (int t = tid; t < PLANE / 4; t += 256) {
        int r  = t / (WW / 4);
        int c4 = (t % (WW / 4)) * 4;
        *(float4*)&in_s[(r + ROW0) * SW + COL0 + c4] = xp[t];
    }
    __syncthreads();

    const int y  = tid >> 2;       // output row
    const int x0 = (tid & 3) << 4; // output col start (0,16,32,48)

    float sL = 0.f, sL2 = 0.f, sS = 0.f, sS2 = 0.f;

    if (y < HH) {
        const int nvalid = (x0 + 16 <= WW) ? 16 : (WW - x0); // 16 or 8
        // ---- large conv: 16 outputs, register sliding window ----
        float acc[16];
        #pragma unroll
        for (int j = 0; j < 16; ++j) acc[j] = 0.f;

        #pragma unroll 1
        for (int ky = 0; ky < 31; ++ky) {
            const float* irow = &in_s[(y + ky) * SW + x0]; // 16B aligned
            float win[48];
            #pragma unroll
            for (int t2 = 0; t2 < 12; ++t2)
                *(float4*)&win[t2 * 4] = *(const float4*)&irow[t2 * 4];
            #pragma unroll
            for (int kx = 0; kx < 31; ++kx) {
                float wv = w_s[ky * 32 + kx];
                #pragma unroll
                for (int j = 0; j < 16; ++j)
                    acc[j] = fmaf(win[j + kx + 1], wv, acc[j]); // pcol = x0+j+kx-15+COL0
            }
        }

        // store yL as bf16 (8B-aligned ushort4 packs; nvalid is 8 or 16)
        __hip_bfloat16* yrow = yL + (size_t)bid * PLANE + y * WW + x0;
        #pragma unroll
        for (int j = 0; j < 16; j += 4) {
            if (j < nvalid) {
                union { ushort4 u4; __hip_bfloat16 h[4]; } pk;
                #pragma unroll
                for (int q = 0; q < 4; ++q) {
                    float v = acc[j + q];
                    pk.h[q] = __float2bfloat16(v);
                    sL += v; sL2 += v * v;
                }
                *(ushort4*)(yrow + j) = pk.u4;
            }
        }

        // ---- small conv (stats only; recomputed in kernel 3) ----
        float accS[16];
        #pragma unroll
        for (int j = 0; j < 16; ++j) accS[j] = 0.f;
        #pragma unroll 1
        for (int ky2 = 0; ky2 < 5; ++ky2) {
            const float* irow = &in_s[(y + ky2 + 13) * SW + x0 + 14]; // pcol = x0+j+kx2-2+COL0
            float win2[20];
            #pragma unroll
            for (int t2 = 0; t2 < 20; ++t2) win2[t2] = irow[t2];
            #pragma unroll
            for (int kx2 = 0; kx2 < 5; ++kx2) {
                float wv = w2_s[ky2 * 5 + kx2];
                #pragma unroll
                for (int j = 0; j < 16; ++j)
                    accS[j] = fmaf(win2[j + kx2], wv, accS[j]);
            }
        }
        #pragma unroll
        for (int j = 0; j < 16; ++j) {
            if (j < nvalid) { float v = accS[j]; sS += v; sS2 += v * v; }
        }
    }

    // ---- block reduce 4 stats -> atomics ----
    #pragma unroll
    for (int off = 32; off > 0; off >>= 1) {
        sL  += __shfl_down(sL,  off);
        sL2 += __shfl_down(sL2, off);
        sS  += __shfl_down(sS,  off);
        sS2 += __shfl_down(sS2, off);
    }
    const int wid  = tid >> 6;
    const int lane = tid & 63;
    if (lane == 0) {
        red_s[wid * 4 + 0] = sL;  red_s[wid * 4 + 1] = sL2;
        red_s[wid * 4 + 2] = sS;  red_s[wid * 4 + 3] = sS2;
    }
    __syncthreads();
    if (tid == 0) {
        float a = 0.f, b = 0.f, d = 0.f, e = 0.f;
        #pragma unroll
        for (int w2 = 0; w2 < 4; ++w2) {
            a += red_s[w2 * 4 + 0]; b += red_s[w2 * 4 + 1];
            d += red_s[w2 * 4 + 2]; e += red_s[w2 * 4 + 3];
        }
        atomicAdd(&stats[c],        a);
        atomicAdd(&stats[384 + c],  b);
        atomicAdd(&stats[768 + c],  d);
        atomicAdd(&stats[1152 + c], e);
    }
}

// ---------------- Kernel 2: BN coefficients ----------------
__global__ void bn_coeffs_k(float* __restrict__ stats,
                            const float* __restrict__ gL, const float* __restrict__ bL,
                            const float* __restrict__ gS, const float* __restrict__ bS)
{
    int c = threadIdx.x;
    if (c < CC) {
        const float inv_n = 1.0f / (float)NHW;
        float mL = stats[c] * inv_n;
        float vL = stats[384 + c] * inv_n - mL * mL;
        float aL = rsqrtf(vL + 1e-5f) * gL[c];
        float mS = stats[768 + c] * inv_n;
        float vS = stats[1152 + c] * inv_n - mS * mS;
        float aS = rsqrtf(vS + 1e-5f) * gS[c];
        stats[1536 + c] = aL;
        stats[1920 + c] = aS;
        stats[2304 + c] = bL[c] + bS[c] - mL * aL - mS * aS;
    }
}

// ---------------- Kernel 3: 5x5 conv + fused affine epilogue ----------------
__global__ __launch_bounds__(256) void fuse_small_k(
    const float* __restrict__ x, const float* __restrict__ wS,
    const __hip_bfloat16* __restrict__ yL, const float* __restrict__ stats,
    float* __restrict__ out)
{
    __shared__ float in_s[60 * ST3]; // 14640 B
    __shared__ float w2_s[25];

    const int bid = blockIdx.x;
    const int c   = bid % CC;
    const int tid = threadIdx.x;

    for (int i = tid; i < 60 * ST3; i += 256) in_s[i] = 0.f;
    if (tid < 25) w2_s[tid] = wS[c * 25 + tid];
    __syncthreads();

    const float4* xp = (const float4*)(x + (size_t)bid * PLANE);
    for (int t = tid; t < PLANE / 4; t += 256) {
        int r  = t / (WW / 4);
        int c4 = (t % (WW / 4)) * 4;
        float4 v = xp[t];
        float* dst = &in_s[(r + 2) * ST3 + 2 + c4];
        dst[0] = v.x; dst[1] = v.y; dst[2] = v.z; dst[3] = v.w;
    }
    __syncthreads();

    const float aL  = stats[1536 + c];
    const float aS  = stats[1920 + c];
    const float cst = stats[2304 + c];
    const __hip_bfloat16* yp = yL + (size_t)bid * PLANE;
    float* op = out + (size_t)bid * PLANE;

    for (int idx = tid; idx < PLANE; idx += 256) {
        int yy = idx / WW;
        int xx = idx - yy * WW;
        float s = 0.f;
        #pragma unroll
        for (int ky = 0; ky < 5; ++ky) {
            #pragma unroll
            for (int kx = 0; kx < 5; ++kx)
                s = fmaf(in_s[(yy + ky) * ST3 + xx + kx], w2_s[ky * 5 + kx], s);
        }
        op[idx] = fmaf(aL, __bfloat162float(yp[idx]), fmaf(aS, s, cst));
    }
}

extern "C" void kernel_launch(void* const* d_in, const int* in_sizes, int n_in,
                              void* d_out, int out_size, void* d_ws, size_t ws_size,
                              hipStream_t stream) {
    const float* x  = (const float*)d_in[0];
    const float* wL = (const float*)d_in[1];
    const float* gL = (const float*)d_in[2];
    const float* bL = (const float*)d_in[3];
    const float* wS = (const float*)d_in[4];
    const float* gS = (const float*)d_in[5];
    const float* bS = (const float*)d_in[6];
    float* out = (float*)d_out;

    __hip_bfloat16* yLbuf = (__hip_bfloat16*)d_ws;
    const size_t yl_bytes = (size_t)BB * CC * PLANE * sizeof(__hip_bfloat16); // 38.5 MB
    float* stats = (float*)((char*)d_ws + yl_bytes);

    hipMemsetAsync(stats, 0, 7 * CC * sizeof(float), stream); // sums + coeffs region

    conv_large_k<<<BB * CC, 256, 0, stream>>>(x, wL, wS, yLbuf, stats);
    bn_coeffs_k<<<1, CC, 0, stream>>>(stats, gL, bL, gS, bS);
    fuse_small_k<<<BB * CC, 256, 0, stream>>>(x, wS, yLbuf, stats, out);
}

// Round 2
// 707.062 us; speedup vs baseline: 1.0741x; 1.0741x over previous
//
#include <hip/hip_runtime.h>
#include <hip/hip_bf16.h>

#define BB 16
#define CC 384
#define HH 56
#define WW 56
#define PLANE (HH*WW)
#define NHW (BB*PLANE)
// SW=108 floats -> granule stride 27 == 3 (mod 8): max 3-way bank collision
// (S=23 gave 4-way; no linear stride achieves 2-way for 16-row x 4-colgroup b128 set)
#define SW 108
#define ROWS 86    // 15 + 56 + 15
#define COL0 16    // center col offset (16B-aligned; halo needs only 15)
#define ROW0 15
#define ST3 61     // kernel3 LDS stride (odd)

// ---------------- Kernel 1: 31x31 depthwise conv + stats (+5x5 stats) ----------------
// __launch_bounds__(256,4): 4 waves/EU -> VGPR cap 128 so win[48]+acc[16] stay live.
// LDS 37.2KB -> 4 blocks/CU -> 16 waves/CU.
__global__ __launch_bounds__(256, 4) void conv_large_k(
    const float* __restrict__ x, const float* __restrict__ wL,
    const float* __restrict__ wS,
    __hip_bfloat16* __restrict__ yL, float* __restrict__ stats)
{
    __shared__ float in_s[ROWS * SW];   // 86*108*4 = 37152 B
    __shared__ float red_s[16];         // 4 waves x 4 stats

    const int bid = blockIdx.x;
    const int c   = bid % CC;
    const int tid = threadIdx.x;

    // weight base pointers -- block-uniform => compiler scalarizes loads (s_load)
    const float* __restrict__ wrow = wL + c * 961;
    const float* __restrict__ w2   = wS + c * 25;

    // zero LDS input buffer (9288 floats, multiple of 4)
    for (int i = tid * 4; i < ROWS * SW; i += 256 * 4) {
        *(float4*)&in_s[i] = make_float4(0.f, 0.f, 0.f, 0.f);
    }
    __syncthreads();

    // load plane center: 784 float4 (56%4==0 so no row crossing)
    const float4* xp = (const float4*)(x + (size_t)bid * PLANE);
    for (int t = tid; t < PLANE / 4; t += 256) {
        int r  = t / (WW / 4);
        int c4 = (t % (WW / 4)) * 4;
        *(float4*)&in_s[(r + ROW0) * SW + COL0 + c4] = xp[t];
    }
    __syncthreads();

    const int y  = tid >> 2;       // output row
    const int x0 = (tid & 3) << 4; // output col start (0,16,32,48)

    float sL = 0.f, sL2 = 0.f, sS = 0.f, sS2 = 0.f;

    if (y < HH) {
        const int nvalid = (x0 + 16 <= WW) ? 16 : (WW - x0); // 16 or 8
        // ---- large conv: 16 outputs, register sliding window ----
        float acc[16];
        #pragma unroll
        for (int j = 0; j < 16; ++j) acc[j] = 0.f;

        #pragma unroll 1
        for (int ky = 0; ky < 31; ++ky) {
            const float* irow = &in_s[(y + ky) * SW + x0]; // 16B aligned
            float win[48];
            #pragma unroll
            for (int t2 = 0; t2 < 12; ++t2)
                *(float4*)&win[t2 * 4] = *(const float4*)&irow[t2 * 4];
            const float* wr = wrow + ky * 31;   // uniform -> SGPR loads
            #pragma unroll
            for (int kx = 0; kx < 31; ++kx) {
                float wv = wr[kx];
                #pragma unroll
                for (int j = 0; j < 16; ++j)
                    acc[j] = fmaf(win[j + kx + 1], wv, acc[j]); // pcol = x0+j+kx-15+COL0
            }
        }

        // store yL as bf16 (8B-aligned ushort4 packs; nvalid is 8 or 16)
        __hip_bfloat16* yrow = yL + (size_t)bid * PLANE + y * WW + x0;
        #pragma unroll
        for (int j = 0; j < 16; j += 4) {
            if (j < nvalid) {
                union { ushort4 u4; __hip_bfloat16 h[4]; } pk;
                #pragma unroll
                for (int q = 0; q < 4; ++q) {
                    float v = acc[j + q];
                    pk.h[q] = __float2bfloat16(v);
                    sL += v; sL2 += v * v;
                }
                *(ushort4*)(yrow + j) = pk.u4;
            }
        }

        // ---- small conv (stats only; recomputed in kernel 3) ----
        // aligned window: read 24 floats (6 x float4) from x0+12; need x0+14..x0+33
        float accS[16];
        #pragma unroll
        for (int j = 0; j < 16; ++j) accS[j] = 0.f;
        #pragma unroll 1
        for (int ky2 = 0; ky2 < 5; ++ky2) {
            const float* irow = &in_s[(y + ky2 + 13) * SW + x0 + 12]; // 16B aligned
            float win2[24];
            #pragma unroll
            for (int t2 = 0; t2 < 6; ++t2)
                *(float4*)&win2[t2 * 4] = *(const float4*)&irow[t2 * 4];
            #pragma unroll
            for (int kx2 = 0; kx2 < 5; ++kx2) {
                float wv = w2[ky2 * 5 + kx2];   // uniform -> SGPR
                #pragma unroll
                for (int j = 0; j < 16; ++j)
                    accS[j] = fmaf(win2[j + kx2 + 2], wv, accS[j]); // pcol = x0+j+kx2-2+COL0
            }
        }
        #pragma unroll
        for (int j = 0; j < 16; ++j) {
            if (j < nvalid) { float v = accS[j]; sS += v; sS2 += v * v; }
        }
    }

    // ---- block reduce 4 stats -> atomics ----
    #pragma unroll
    for (int off = 32; off > 0; off >>= 1) {
        sL  += __shfl_down(sL,  off);
        sL2 += __shfl_down(sL2, off);
        sS  += __shfl_down(sS,  off);
        sS2 += __shfl_down(sS2, off);
    }
    const int wid  = tid >> 6;
    const int lane = tid & 63;
    if (lane == 0) {
        red_s[wid * 4 + 0] = sL;  red_s[wid * 4 + 1] = sL2;
        red_s[wid * 4 + 2] = sS;  red_s[wid * 4 + 3] = sS2;
    }
    __syncthreads();
    if (tid == 0) {
        float a = 0.f, b = 0.f, d = 0.f, e = 0.f;
        #pragma unroll
        for (int w2i = 0; w2i < 4; ++w2i) {
            a += red_s[w2i * 4 + 0]; b += red_s[w2i * 4 + 1];
            d += red_s[w2i * 4 + 2]; e += red_s[w2i * 4 + 3];
        }
        atomicAdd(&stats[c],        a);
        atomicAdd(&stats[384 + c],  b);
        atomicAdd(&stats[768 + c],  d);
        atomicAdd(&stats[1152 + c], e);
    }
}

// ---------------- Kernel 2: BN coefficients ----------------
__global__ void bn_coeffs_k(float* __restrict__ stats,
                            const float* __restrict__ gL, const float* __restrict__ bL,
                            const float* __restrict__ gS, const float* __restrict__ bS)
{
    int c = threadIdx.x;
    if (c < CC) {
        const float inv_n = 1.0f / (float)NHW;
        float mL = stats[c] * inv_n;
        float vL = stats[384 + c] * inv_n - mL * mL;
        float aL = rsqrtf(vL + 1e-5f) * gL[c];
        float mS = stats[768 + c] * inv_n;
        float vS = stats[1152 + c] * inv_n - mS * mS;
        float aS = rsqrtf(vS + 1e-5f) * gS[c];
        stats[1536 + c] = aL;
        stats[1920 + c] = aS;
        stats[2304 + c] = bL[c] + bS[c] - mL * aL - mS * aS;
    }
}

// ---------------- Kernel 3: 5x5 conv + fused affine epilogue ----------------
__global__ __launch_bounds__(256) void fuse_small_k(
    const float* __restrict__ x, const float* __restrict__ wS,
    const __hip_bfloat16* __restrict__ yL, const float* __restrict__ stats,
    float* __restrict__ out)
{
    __shared__ float in_s[60 * ST3]; // 14640 B

    const int bid = blockIdx.x;
    const int c   = bid % CC;
    const int tid = threadIdx.x;

    const float* __restrict__ w2 = wS + c * 25;  // uniform -> SGPR

    for (int i = tid; i < 60 * ST3; i += 256) in_s[i] = 0.f;
    __syncthreads();

    const float4* xp = (const float4*)(x + (size_t)bid * PLANE);
    for (int t = tid; t < PLANE / 4; t += 256) {
        int r  = t / (WW / 4);
        int c4 = (t % (WW / 4)) * 4;
        float4 v = xp[t];
        float* dst = &in_s[(r + 2) * ST3 + 2 + c4];
        dst[0] = v.x; dst[1] = v.y; dst[2] = v.z; dst[3] = v.w;
    }
    __syncthreads();

    const float aL  = stats[1536 + c];
    const float aS  = stats[1920 + c];
    const float cst = stats[2304 + c];
    const __hip_bfloat16* yp = yL + (size_t)bid * PLANE;
    float* op = out + (size_t)bid * PLANE;

    for (int idx = tid; idx < PLANE; idx += 256) {
        int yy = idx / WW;
        int xx = idx - yy * WW;
        float s = 0.f;
        #pragma unroll
        for (int ky = 0; ky < 5; ++ky) {
            #pragma unroll
            for (int kx = 0; kx < 5; ++kx)
                s = fmaf(in_s[(yy + ky) * ST3 + xx + kx], w2[ky * 5 + kx], s);
        }
        op[idx] = fmaf(aL, __bfloat162float(yp[idx]), fmaf(aS, s, cst));
    }
}

extern "C" void kernel_launch(void* const* d_in, const int* in_sizes, int n_in,
                              void* d_out, int out_size, void* d_ws, size_t ws_size,
                              hipStream_t stream) {
    const float* x  = (const float*)d_in[0];
    const float* wL = (const float*)d_in[1];
    const float* gL = (const float*)d_in[2];
    const float* bL = (const float*)d_in[3];
    const float* wS = (const float*)d_in[4];
    const float* gS = (const float*)d_in[5];
    const float* bS = (const float*)d_in[6];
    float* out = (float*)d_out;

    __hip_bfloat16* yLbuf = (__hip_bfloat16*)d_ws;
    const size_t yl_bytes = (size_t)BB * CC * PLANE * sizeof(__hip_bfloat16); // 38.5 MB
    float* stats = (float*)((char*)d_ws + yl_bytes);

    hipMemsetAsync(stats, 0, 7 * CC * sizeof(float), stream); // sums + coeffs region

    conv_large_k<<<BB * CC, 256, 0, stream>>>(x, wL, wS, yLbuf, stats);
    bn_coeffs_k<<<1, CC, 0, stream>>>(stats, gL, bL, gS, bS);
    fuse_small_k<<<BB * CC, 256, 0, stream>>>(x, wS, yLbuf, stats, out);
}